// Round 6
// baseline (1042.142 us; speedup 1.0000x reference)
//
#include <hip/hip_runtime.h>

// EfficientAttention MI355X — round 9:
//  * k_fused: flat ping-pong double-buffer of x chunks (macro-pasted straight-
//    line code; round 7's identical idea failed ONLY because lambda-captured
//    arrays went to scratch: VGPR 84, +580 MB spill traffic). Channel order
//    unchanged -> bit-identical. Decl stays __launch_bounds__(256) for a clean
//    A/B vs the 365 us round-5 body.
//  * k_out: round-8 LDS-staged M (kept, +18 us).
//  * k_combine: parallel (72 blocks). k_prep unchanged.

#define NV 131072
#define CC 96
#define NB 2
#define HK 24
#define PAD 68
#define BPN 384          // k_fused blocks per batch index
#define TILES_N 2048     // 64-position tiles per batch index

// ---------------------------------------------------------------- kernel 0
__global__ __launch_bounds__(256) void k_prep(
    const float* __restrict__ Wq, const float* __restrict__ Wk,
    const float* __restrict__ Wv,
    float* __restrict__ Wqt, float* __restrict__ Wkt, float* __restrict__ Wvt)
{
    const int i = blockIdx.x * 256 + threadIdx.x;
    if (i >= CC * CC) return;
    const int h = i / (HK * CC);
    const int r = i % (HK * CC);
    const int c = r / HK;
    const int j = r % HK;
    const int src = (h * HK + j) * CC + c;
    Wqt[i] = Wq[src];
    Wkt[i] = Wk[src];
    Wvt[i] = Wv[src];
}

// flat load/consume macros — plain statements, literal chunk bases, no lambdas
#define XLOAD(buf, base, cb)                                            \
    _Pragma("unroll")                                                   \
    for (int u = 0; u < 16; ++u)                                        \
        buf[u] = x[(base) + (size_t)((cb) + u) * NV];

#define XCONS(buf, cb)                                                  \
    _Pragma("unroll")                                                   \
    for (int u = 0; u < 16; ++u) {                                      \
        const int c_ = (cb) + u;                                        \
        const float xv_ = buf[u];                                       \
        _Pragma("unroll")                                               \
        for (int j = 0; j < HK; ++j) {                                  \
            aq[j] = fmaf(Wqh[c_ * HK + j], xv_, aq[j]);                 \
            ak[j] = fmaf(Wkh[c_ * HK + j], xv_, ak[j]);                 \
            av[j] = fmaf(Wvh[c_ * HK + j], xv_, av[j]);                 \
        }                                                               \
    }

// ---------------------------------------------------------------- kernel 1
__global__ __launch_bounds__(256) void k_fused(
    const float* __restrict__ x,
    const float* __restrict__ Wqt, const float* __restrict__ bq,
    const float* __restrict__ Wkt, const float* __restrict__ bk,
    const float* __restrict__ Wvt, const float* __restrict__ bv,
    float* __restrict__ qsm, float* __restrict__ ctx, float* __restrict__ ksum)
{
    __shared__ float eks[4 * HK * PAD];   // per-wave exp(k) tiles [24][68]
    __shared__ float vls[4 * HK * PAD];   // per-wave v tiles      [24][68]
    const int tid = threadIdx.x;
    const int pl  = tid & 63;
    const int gu  = __builtin_amdgcn_readfirstlane(tid >> 6);  // wave = head
    const int n   = blockIdx.x / BPN;
    const int r0  = blockIdx.x % BPN;
    const int a   = pl >> 3, b = pl & 7;  // 8x8 lane grid for 3x3 ctx tile

    float* __restrict__ ek = eks + gu * HK * PAD;
    float* __restrict__ vl = vls + gu * HK * PAD;
    const float* __restrict__ Wqh = Wqt + gu * HK * CC;  // [c][j] contiguous
    const float* __restrict__ Wkh = Wkt + gu * HK * CC;
    const float* __restrict__ Wvh = Wvt + gu * HK * CC;

    float cacc[9];
#pragma unroll
    for (int k = 0; k < 9; ++k) cacc[k] = 0.f;
    float ksacc = 0.f;

    float aq[HK], ak[HK], av[HK];
    float xr0[16], xr1[16];

    // prologue: chunk 0 of first tile
    size_t xb = (size_t)n * CC * NV + (size_t)r0 * 64 + pl;
    XLOAD(xr0, xb, 0)

    for (int tt = r0; tt < TILES_N; tt += BPN) {
        const size_t xbn = xb + (size_t)BPN * 64;   // next tile's base

#pragma unroll
        for (int j = 0; j < HK; ++j) {
            aq[j] = bq[gu * HK + j];
            ak[j] = bk[gu * HK + j];
            av[j] = bv[gu * HK + j];
        }

        // ---- ping-pong: load chunk c+1 while consuming chunk c (flat)
        XLOAD(xr1, xb, 16)  XCONS(xr0, 0)
        XLOAD(xr0, xb, 32)  XCONS(xr1, 16)
        XLOAD(xr1, xb, 48)  XCONS(xr0, 32)
        XLOAD(xr0, xb, 64)  XCONS(xr1, 48)
        XLOAD(xr1, xb, 80)  XCONS(xr0, 64)
        if (tt + BPN < TILES_N) { XLOAD(xr0, xbn, 0) }  // next tile chunk 0
        XCONS(xr1, 80)
        xb = xbn;

        // ---- q softmax (registers) -> qsm
        {
            float mx = aq[0];
#pragma unroll
            for (int j = 1; j < HK; ++j) mx = fmaxf(mx, aq[j]);
            float s = 0.f;
#pragma unroll
            for (int j = 0; j < HK; ++j) { aq[j] = __expf(aq[j] - mx); s += aq[j]; }
            const float inv = 1.f / s;
            const size_t qb = ((size_t)n * CC + gu * HK) * NV + (size_t)tt * 64 + pl;
#pragma unroll
            for (int j = 0; j < HK; ++j)
                qsm[qb + (size_t)j * NV] = aq[j] * inv;
        }

        // ---- exp(k) and v into this wave's private LDS (no barrier needed)
#pragma unroll
        for (int j = 0; j < HK; ++j) ek[j * PAD + pl] = __expf(ak[j]);
#pragma unroll
        for (int j = 0; j < HK; ++j) vl[j * PAD + pl] = av[j];

        // ---- ksum: lane < 24 sums its exp(k) row
        if (pl < HK) {
            const float4* __restrict__ rp = (const float4*)(ek + pl * PAD);
            float s = 0.f;
#pragma unroll
            for (int q = 0; q < 16; ++q) {
                const float4 t = rp[q];
                s += t.x + t.y + t.z + t.w;
            }
            ksacc += s;
        }

        // ---- context outer product: 3x3 register tile per lane
#pragma unroll
        for (int q = 0; q < 16; ++q) {
            float4 e4[3], v4[3];
#pragma unroll
            for (int i = 0; i < 3; ++i)
                e4[i] = ((const float4*)(ek + (a + 8 * i) * PAD))[q];
#pragma unroll
            for (int j = 0; j < 3; ++j)
                v4[j] = ((const float4*)(vl + (b + 8 * j) * PAD))[q];
#pragma unroll
            for (int i = 0; i < 3; ++i)
#pragma unroll
                for (int j = 0; j < 3; ++j) {
                    float t = cacc[i * 3 + j];
                    t = fmaf(e4[i].x, v4[j].x, t);
                    t = fmaf(e4[i].y, v4[j].y, t);
                    t = fmaf(e4[i].z, v4[j].z, t);
                    t = fmaf(e4[i].w, v4[j].w, t);
                    cacc[i * 3 + j] = t;
                }
        }
    }

    // ---- one atomic flush per block
#pragma unroll
    for (int i = 0; i < 3; ++i)
#pragma unroll
        for (int j = 0; j < 3; ++j)
            atomicAdd(&ctx[((size_t)n * CC + gu * HK + a + 8 * i) * HK + b + 8 * j],
                      cacc[i * 3 + j]);
    if (pl < HK) atomicAdd(&ksum[n * CC + gu * HK + pl], ksacc);
}

// ---------------------------------------------------------------- kernel 2
// Mnt[n][kg][o]; one thread per output (72 blocks x 256 = 2*96*96 exactly)
__global__ __launch_bounds__(256) void k_combine(
    const float* __restrict__ Wr, const float* __restrict__ ctx,
    const float* __restrict__ ksum, float* __restrict__ Mnt)
{
    const int g  = blockIdx.x * 256 + threadIdx.x;
    const int n  = g / (CC * CC);
    const int r  = g % (CC * CC);
    const int kg = r / CC;
    const int o  = r % CC;
    const int h  = kg / HK;
    float a = 0.f;
#pragma unroll
    for (int v = 0; v < HK; ++v)
        a += Wr[o * CC + h * HK + v] * ctx[((size_t)n * CC + kg) * HK + v];
    Mnt[((size_t)n * CC + kg) * CC + o] = a / ksum[n * CC + kg];
}

// ---------------------------------------------------------------- kernel 3
// out[n][o][p] = sum_q Mnt[n][q][o] * qsm[n][q][p] + br[o]
// Wave w -> o in [24w, 24w+24); lane = position; 2 positions per lane.
// M[n] (36 KB) staged in LDS once per block; per-q row slice is a broadcast
// ds_read_b128 x6.
__global__ __launch_bounds__(256) void k_out(
    const float* __restrict__ qsm, const float* __restrict__ Mnt,
    const float* __restrict__ br, float* __restrict__ out)
{
    __shared__ float lm[CC * CC];              // 36864 B -> 4 blocks/CU
    const int tid = threadIdx.x;
    const int pl  = tid & 63;
    const int w   = __builtin_amdgcn_readfirstlane(tid >> 6);  // wave = o-group
    const int n   = blockIdx.x >> 10;          // grid = NB * (NV/128) = 2048
    const int pt  = blockIdx.x & 1023;
    const size_t p0 = (size_t)pt * 128 + pl;

    // stage M[n] into LDS (coalesced float4, 9 per thread)
    {
        const float4* __restrict__ Ms = (const float4*)(Mnt + (size_t)n * CC * CC);
        float4* __restrict__ ld4 = (float4*)lm;
#pragma unroll
        for (int i = 0; i < 9; ++i)
            ld4[tid + 256 * i] = Ms[tid + 256 * i];
    }
    __syncthreads();

    const float* __restrict__ mbase = lm + w * HK;   // this wave's 24-col slice
    const float* __restrict__ qb = qsm + (size_t)n * CC * NV + p0;

    float a0[HK], a1[HK];
#pragma unroll
    for (int j = 0; j < HK; ++j) { a0[j] = br[w * HK + j]; a1[j] = a0[j]; }

#pragma unroll 4
    for (int q = 0; q < CC; ++q) {
        const float q0 = qb[(size_t)q * NV];
        const float q1 = qb[(size_t)q * NV + 64];
        const float4* __restrict__ m4 = (const float4*)(mbase + q * CC);  // 16B-aligned
        float4 mv[6];
#pragma unroll
        for (int t = 0; t < 6; ++t) mv[t] = m4[t];
#pragma unroll
        for (int t = 0; t < 6; ++t) {
            a0[4 * t + 0] = fmaf(mv[t].x, q0, a0[4 * t + 0]);
            a0[4 * t + 1] = fmaf(mv[t].y, q0, a0[4 * t + 1]);
            a0[4 * t + 2] = fmaf(mv[t].z, q0, a0[4 * t + 2]);
            a0[4 * t + 3] = fmaf(mv[t].w, q0, a0[4 * t + 3]);
            a1[4 * t + 0] = fmaf(mv[t].x, q1, a1[4 * t + 0]);
            a1[4 * t + 1] = fmaf(mv[t].y, q1, a1[4 * t + 1]);
            a1[4 * t + 2] = fmaf(mv[t].z, q1, a1[4 * t + 2]);
            a1[4 * t + 3] = fmaf(mv[t].w, q1, a1[4 * t + 3]);
        }
    }

    float* __restrict__ ob = out + ((size_t)n * CC + (size_t)w * HK) * NV + p0;
#pragma unroll
    for (int j = 0; j < HK; ++j) {
        ob[(size_t)j * NV]      = a0[j];
        ob[(size_t)j * NV + 64] = a1[j];
    }
}

// ---------------------------------------------------------------- launch
extern "C" void kernel_launch(void* const* d_in, const int* in_sizes, int n_in,
                              void* d_out, int out_size, void* d_ws, size_t ws_size,
                              hipStream_t stream) {
    const float* x  = (const float*)d_in[0];
    const float* Wk = (const float*)d_in[1];
    const float* bk = (const float*)d_in[2];
    const float* Wq = (const float*)d_in[3];
    const float* bq = (const float*)d_in[4];
    const float* Wv = (const float*)d_in[5];
    const float* bv = (const float*)d_in[6];
    const float* Wr = (const float*)d_in[7];
    const float* br = (const float*)d_in[8];
    float* out = (float*)d_out;

    float* ws = (float*)d_ws;
    const size_t BIG = (size_t)NB * CC * NV;     // 25,165,824 floats
    float* qsm  = ws;                            // [2,96,NV]
    float* ctx  = ws + BIG;                      // [2,96,24] = 4608
    float* ksum = ctx + (size_t)NB * CC * HK;    // [2,96]    = 192
    float* Mnt  = ksum + (size_t)NB * CC;        // [2,96,96] = 18432
    float* Wqt  = Mnt + (size_t)NB * CC * CC;    // [4,96,24] = 9216
    float* Wkt  = Wqt + CC * CC;
    float* Wvt  = Wkt + CC * CC;

    // zero atomic accumulators (ctx+ksum contiguous)
    hipMemsetAsync(ctx, 0, ((size_t)NB * CC * HK + (size_t)NB * CC) * sizeof(float), stream);

    k_prep<<<dim3((CC * CC + 255) / 256), dim3(256), 0, stream>>>(Wq, Wk, Wv, Wqt, Wkt, Wvt);
    k_fused<<<dim3(NB * BPN), dim3(256), 0, stream>>>(x, Wqt, bq, Wkt, bk, Wvt, bv, qsm, ctx, ksum);
    k_combine<<<dim3(NB * CC * CC / 256), dim3(256), 0, stream>>>(Wr, ctx, ksum, Mnt);
    k_out<<<dim3(NB * 1024), dim3(256), 0, stream>>>(qsm, Mnt, br, out);
}

// Round 7
// 547.649 us; speedup vs baseline: 1.9029x; 1.9029x over previous
//
#include <hip/hip_runtime.h>

// EfficientAttention MI355X — round 10:
//  * k_fused: VERBATIM round-5 body (365 us verified; three restructures all
//    regressed: 421/721/851 — do not touch).
//  * k_out: 4 contiguous positions/thread via float4 qsm loads (halves load
//    instrs, FMA:load = 96:1, 1-deep prefetch), M[n] staged in LDS (round 8).
//    Same q-accumulation order -> bit-identical. 1024 blocks.
//  * k_combine: parallel (72 blocks). k_prep unchanged.

#define NV 131072
#define CC 96
#define NB 2
#define HK 24
#define PAD 68
#define BPN 384          // k_fused blocks per batch index
#define TILES_N 2048     // 64-position tiles per batch index

// ---------------------------------------------------------------- kernel 0
__global__ __launch_bounds__(256) void k_prep(
    const float* __restrict__ Wq, const float* __restrict__ Wk,
    const float* __restrict__ Wv,
    float* __restrict__ Wqt, float* __restrict__ Wkt, float* __restrict__ Wvt)
{
    const int i = blockIdx.x * 256 + threadIdx.x;
    if (i >= CC * CC) return;
    const int h = i / (HK * CC);
    const int r = i % (HK * CC);
    const int c = r / HK;
    const int j = r % HK;
    const int src = (h * HK + j) * CC + c;
    Wqt[i] = Wq[src];
    Wkt[i] = Wk[src];
    Wvt[i] = Wv[src];
}

// ---------------------------------------------------------------- kernel 1
__global__ __launch_bounds__(256) void k_fused(
    const float* __restrict__ x,
    const float* __restrict__ Wqt, const float* __restrict__ bq,
    const float* __restrict__ Wkt, const float* __restrict__ bk,
    const float* __restrict__ Wvt, const float* __restrict__ bv,
    float* __restrict__ qsm, float* __restrict__ ctx, float* __restrict__ ksum)
{
    __shared__ float eks[4 * HK * PAD];   // per-wave exp(k) tiles [24][68]
    __shared__ float vls[4 * HK * PAD];   // per-wave v tiles      [24][68]
    const int tid = threadIdx.x;
    const int pl  = tid & 63;
    const int gu  = __builtin_amdgcn_readfirstlane(tid >> 6);  // wave = head
    const int n   = blockIdx.x / BPN;
    const int r0  = blockIdx.x % BPN;
    const int a   = pl >> 3, b = pl & 7;  // 8x8 lane grid for 3x3 ctx tile

    float* __restrict__ ek = eks + gu * HK * PAD;
    float* __restrict__ vl = vls + gu * HK * PAD;
    const float* __restrict__ Wqh = Wqt + gu * HK * CC;  // [c][j] contiguous
    const float* __restrict__ Wkh = Wkt + gu * HK * CC;
    const float* __restrict__ Wvh = Wvt + gu * HK * CC;

    float cacc[9];
#pragma unroll
    for (int k = 0; k < 9; ++k) cacc[k] = 0.f;
    float ksacc = 0.f;

    for (int tt = r0; tt < TILES_N; tt += BPN) {
        const size_t xb = (size_t)n * CC * NV + (size_t)tt * 64 + pl;

        // ---- projections: 72 simultaneous accumulators, x in 16-reg chunks
        float aq[HK], ak[HK], av[HK];
#pragma unroll
        for (int j = 0; j < HK; ++j) {
            aq[j] = bq[gu * HK + j];
            ak[j] = bk[gu * HK + j];
            av[j] = bv[gu * HK + j];
        }
        for (int ch = 0; ch < 6; ++ch) {
            float xr[16];
#pragma unroll
            for (int u = 0; u < 16; ++u)
                xr[u] = x[xb + (size_t)(ch * 16 + u) * NV];
#pragma unroll
            for (int u = 0; u < 16; ++u) {
                const int c = ch * 16 + u;
#pragma unroll
                for (int j = 0; j < HK; ++j) {
                    aq[j] = fmaf(Wqh[c * HK + j], xr[u], aq[j]);
                    ak[j] = fmaf(Wkh[c * HK + j], xr[u], ak[j]);
                    av[j] = fmaf(Wvh[c * HK + j], xr[u], av[j]);
                }
            }
        }

        // ---- q softmax (registers) -> qsm
        {
            float mx = aq[0];
#pragma unroll
            for (int j = 1; j < HK; ++j) mx = fmaxf(mx, aq[j]);
            float s = 0.f;
#pragma unroll
            for (int j = 0; j < HK; ++j) { aq[j] = __expf(aq[j] - mx); s += aq[j]; }
            const float inv = 1.f / s;
            const size_t qb = ((size_t)n * CC + gu * HK) * NV + (size_t)tt * 64 + pl;
#pragma unroll
            for (int j = 0; j < HK; ++j)
                qsm[qb + (size_t)j * NV] = aq[j] * inv;
        }

        // ---- exp(k) and v into this wave's private LDS (no barrier needed)
#pragma unroll
        for (int j = 0; j < HK; ++j) ek[j * PAD + pl] = __expf(ak[j]);
#pragma unroll
        for (int j = 0; j < HK; ++j) vl[j * PAD + pl] = av[j];

        // ---- ksum: lane < 24 sums its exp(k) row
        if (pl < HK) {
            const float4* __restrict__ rp = (const float4*)(ek + pl * PAD);
            float s = 0.f;
#pragma unroll
            for (int q = 0; q < 16; ++q) {
                const float4 t = rp[q];
                s += t.x + t.y + t.z + t.w;
            }
            ksacc += s;
        }

        // ---- context outer product: 3x3 register tile per lane
#pragma unroll
        for (int q = 0; q < 16; ++q) {
            float4 e4[3], v4[3];
#pragma unroll
            for (int i = 0; i < 3; ++i)
                e4[i] = ((const float4*)(ek + (a + 8 * i) * PAD))[q];
#pragma unroll
            for (int j = 0; j < 3; ++j)
                v4[j] = ((const float4*)(vl + (b + 8 * j) * PAD))[q];
#pragma unroll
            for (int i = 0; i < 3; ++i)
#pragma unroll
                for (int j = 0; j < 3; ++j) {
                    float t = cacc[i * 3 + j];
                    t = fmaf(e4[i].x, v4[j].x, t);
                    t = fmaf(e4[i].y, v4[j].y, t);
                    t = fmaf(e4[i].z, v4[j].z, t);
                    t = fmaf(e4[i].w, v4[j].w, t);
                    cacc[i * 3 + j] = t;
                }
        }
    }

    // ---- one atomic flush per block
#pragma unroll
    for (int i = 0; i < 3; ++i)
#pragma unroll
        for (int j = 0; j < 3; ++j)
            atomicAdd(&ctx[((size_t)n * CC + gu * HK + a + 8 * i) * HK + b + 8 * j],
                      cacc[i * 3 + j]);
    if (pl < HK) atomicAdd(&ksum[n * CC + gu * HK + pl], ksacc);
}

// ---------------------------------------------------------------- kernel 2
// Mnt[n][kg][o]; one thread per output (72 blocks x 256 = 2*96*96 exactly)
__global__ __launch_bounds__(256) void k_combine(
    const float* __restrict__ Wr, const float* __restrict__ ctx,
    const float* __restrict__ ksum, float* __restrict__ Mnt)
{
    const int g  = blockIdx.x * 256 + threadIdx.x;
    const int n  = g / (CC * CC);
    const int r  = g % (CC * CC);
    const int kg = r / CC;
    const int o  = r % CC;
    const int h  = kg / HK;
    float a = 0.f;
#pragma unroll
    for (int v = 0; v < HK; ++v)
        a += Wr[o * CC + h * HK + v] * ctx[((size_t)n * CC + kg) * HK + v];
    Mnt[((size_t)n * CC + kg) * CC + o] = a / ksum[n * CC + kg];
}

// ---------------------------------------------------------------- kernel 3
// out[n][o][p] = sum_q Mnt[n][q][o] * qsm[n][q][p] + br[o]
// Wave w -> o in [24w, 24w+24); thread = 4 contiguous positions (float4).
// M[n] staged in LDS; per-q slice = 6 broadcast ds_read_b128; qsm via one
// coalesced dwordx4 per q-step with 1-deep prefetch. 1024 blocks.
__global__ __launch_bounds__(256) void k_out(
    const float* __restrict__ qsm, const float* __restrict__ Mnt,
    const float* __restrict__ br, float* __restrict__ out)
{
    __shared__ float lm[CC * CC];              // 36864 B
    const int tid = threadIdx.x;
    const int pl  = tid & 63;
    const int w   = __builtin_amdgcn_readfirstlane(tid >> 6);  // wave = o-group
    const int n   = blockIdx.x >> 9;           // grid = NB * (NV/256) = 1024
    const int pt  = blockIdx.x & 511;
    const size_t p0 = (size_t)pt * 256 + (size_t)pl * 4;   // 4 consecutive pos

    // stage M[n] into LDS (coalesced float4, 9 per thread)
    {
        const float4* __restrict__ Ms = (const float4*)(Mnt + (size_t)n * CC * CC);
        float4* __restrict__ ld4 = (float4*)lm;
#pragma unroll
        for (int i = 0; i < 9; ++i)
            ld4[tid + 256 * i] = Ms[tid + 256 * i];
    }
    __syncthreads();

    const float* __restrict__ mbase = lm + w * HK;   // this wave's 24-col slice
    const float4* __restrict__ qb4 =
        (const float4*)(qsm + (size_t)n * CC * NV) + (p0 >> 2);

    float4 acc[HK];
#pragma unroll
    for (int j = 0; j < HK; ++j) {
        const float b = br[w * HK + j];
        acc[j].x = b; acc[j].y = b; acc[j].z = b; acc[j].w = b;
    }

    float4 cq = qb4[0];
#pragma unroll 2
    for (int q = 0; q < CC - 1; ++q) {
        const float4 nq = qb4[(size_t)(q + 1) * (NV / 4)];   // prefetch next q
        const float4* __restrict__ m4 = (const float4*)(mbase + q * CC);
        float4 mv[6];
#pragma unroll
        for (int t = 0; t < 6; ++t) mv[t] = m4[t];
#pragma unroll
        for (int t = 0; t < 6; ++t) {
            acc[4 * t + 0].x = fmaf(mv[t].x, cq.x, acc[4 * t + 0].x);
            acc[4 * t + 0].y = fmaf(mv[t].x, cq.y, acc[4 * t + 0].y);
            acc[4 * t + 0].z = fmaf(mv[t].x, cq.z, acc[4 * t + 0].z);
            acc[4 * t + 0].w = fmaf(mv[t].x, cq.w, acc[4 * t + 0].w);
            acc[4 * t + 1].x = fmaf(mv[t].y, cq.x, acc[4 * t + 1].x);
            acc[4 * t + 1].y = fmaf(mv[t].y, cq.y, acc[4 * t + 1].y);
            acc[4 * t + 1].z = fmaf(mv[t].y, cq.z, acc[4 * t + 1].z);
            acc[4 * t + 1].w = fmaf(mv[t].y, cq.w, acc[4 * t + 1].w);
            acc[4 * t + 2].x = fmaf(mv[t].z, cq.x, acc[4 * t + 2].x);
            acc[4 * t + 2].y = fmaf(mv[t].z, cq.y, acc[4 * t + 2].y);
            acc[4 * t + 2].z = fmaf(mv[t].z, cq.z, acc[4 * t + 2].z);
            acc[4 * t + 2].w = fmaf(mv[t].z, cq.w, acc[4 * t + 2].w);
            acc[4 * t + 3].x = fmaf(mv[t].w, cq.x, acc[4 * t + 3].x);
            acc[4 * t + 3].y = fmaf(mv[t].w, cq.y, acc[4 * t + 3].y);
            acc[4 * t + 3].z = fmaf(mv[t].w, cq.z, acc[4 * t + 3].z);
            acc[4 * t + 3].w = fmaf(mv[t].w, cq.w, acc[4 * t + 3].w);
        }
        cq = nq;
    }
    {   // final q = 95 (no prefetch)
        const float4* __restrict__ m4 = (const float4*)(mbase + (CC - 1) * CC);
        float4 mv[6];
#pragma unroll
        for (int t = 0; t < 6; ++t) mv[t] = m4[t];
#pragma unroll
        for (int t = 0; t < 6; ++t) {
            acc[4 * t + 0].x = fmaf(mv[t].x, cq.x, acc[4 * t + 0].x);
            acc[4 * t + 0].y = fmaf(mv[t].x, cq.y, acc[4 * t + 0].y);
            acc[4 * t + 0].z = fmaf(mv[t].x, cq.z, acc[4 * t + 0].z);
            acc[4 * t + 0].w = fmaf(mv[t].x, cq.w, acc[4 * t + 0].w);
            acc[4 * t + 1].x = fmaf(mv[t].y, cq.x, acc[4 * t + 1].x);
            acc[4 * t + 1].y = fmaf(mv[t].y, cq.y, acc[4 * t + 1].y);
            acc[4 * t + 1].z = fmaf(mv[t].y, cq.z, acc[4 * t + 1].z);
            acc[4 * t + 1].w = fmaf(mv[t].y, cq.w, acc[4 * t + 1].w);
            acc[4 * t + 2].x = fmaf(mv[t].z, cq.x, acc[4 * t + 2].x);
            acc[4 * t + 2].y = fmaf(mv[t].z, cq.y, acc[4 * t + 2].y);
            acc[4 * t + 2].z = fmaf(mv[t].z, cq.z, acc[4 * t + 2].z);
            acc[4 * t + 2].w = fmaf(mv[t].z, cq.w, acc[4 * t + 2].w);
            acc[4 * t + 3].x = fmaf(mv[t].w, cq.x, acc[4 * t + 3].x);
            acc[4 * t + 3].y = fmaf(mv[t].w, cq.y, acc[4 * t + 3].y);
            acc[4 * t + 3].z = fmaf(mv[t].w, cq.z, acc[4 * t + 3].z);
            acc[4 * t + 3].w = fmaf(mv[t].w, cq.w, acc[4 * t + 3].w);
        }
    }

    float4* __restrict__ ob =
        (float4*)(out + ((size_t)n * CC + (size_t)w * HK) * NV) + (p0 >> 2);
#pragma unroll
    for (int j = 0; j < HK; ++j)
        ob[(size_t)j * (NV / 4)] = acc[j];
}

// ---------------------------------------------------------------- launch
extern "C" void kernel_launch(void* const* d_in, const int* in_sizes, int n_in,
                              void* d_out, int out_size, void* d_ws, size_t ws_size,
                              hipStream_t stream) {
    const float* x  = (const float*)d_in[0];
    const float* Wk = (const float*)d_in[1];
    const float* bk = (const float*)d_in[2];
    const float* Wq = (const float*)d_in[3];
    const float* bq = (const float*)d_in[4];
    const float* Wv = (const float*)d_in[5];
    const float* bv = (const float*)d_in[6];
    const float* Wr = (const float*)d_in[7];
    const float* br = (const float*)d_in[8];
    float* out = (float*)d_out;

    float* ws = (float*)d_ws;
    const size_t BIG = (size_t)NB * CC * NV;     // 25,165,824 floats
    float* qsm  = ws;                            // [2,96,NV]
    float* ctx  = ws + BIG;                      // [2,96,24] = 4608
    float* ksum = ctx + (size_t)NB * CC * HK;    // [2,96]    = 192
    float* Mnt  = ksum + (size_t)NB * CC;        // [2,96,96] = 18432
    float* Wqt  = Mnt + (size_t)NB * CC * CC;    // [4,96,24] = 9216
    float* Wkt  = Wqt + CC * CC;
    float* Wvt  = Wkt + CC * CC;

    // zero atomic accumulators (ctx+ksum contiguous)
    hipMemsetAsync(ctx, 0, ((size_t)NB * CC * HK + (size_t)NB * CC) * sizeof(float), stream);

    k_prep<<<dim3((CC * CC + 255) / 256), dim3(256), 0, stream>>>(Wq, Wk, Wv, Wqt, Wkt, Wvt);
    k_fused<<<dim3(NB * BPN), dim3(256), 0, stream>>>(x, Wqt, bq, Wkt, bk, Wvt, bv, qsm, ctx, ksum);
    k_combine<<<dim3(NB * CC * CC / 256), dim3(256), 0, stream>>>(Wr, ctx, ksum, Mnt);
    k_out<<<dim3(NB * 512), dim3(256), 0, stream>>>(qsm, Mnt, br, out);
}